// Round 5
// baseline (105.776 us; speedup 1.0000x reference)
//
#include <hip/hip_runtime.h>
#include <hip/hip_bf16.h>

// CenterLoss: loss = ( sum_i clamp(||x_i - c_{label_i}||^2, 1e-12, 1e12)
//                      + B*(C-1)*1e-12 ) / B
// R1: 110us -- serialized same-address atomics.
// R2/R3: partials + tree-reduce, ~22-25us kernel time inside ~80us fixed
//        harness envelope (256MB 0xAA ws-poison + d_in restore dominate).
// R4: VGPR_Count=12 => only ~2 loads in flight per lane (latency-serialized).
//     Stage all 16 float4 loads into registers before the FMA chain;
//     nontemporal on x (streaming; centers stay cached, ~11x reuse).
// R5: fix compile -- __builtin_nontemporal_load needs a clang ext_vector_type,
//     not HIP_vector_type<float,4>.

#define BATCH 8192
#define NUM_CLASSES 751
#define FEAT_DIM 2048
#define NB 2048          // 4 waves/block, 1 row/wave -> 8192 rows exact

typedef float fvec4 __attribute__((ext_vector_type(4)));

__global__ __launch_bounds__(256) void center_loss_main(
        const float* __restrict__ x,
        const int* __restrict__ labels,
        const float* __restrict__ centers,
        float* __restrict__ partial) {
    const int t = threadIdx.x;
    const int wave = t >> 6;
    const int lane = t & 63;
    const int row = blockIdx.x * 4 + wave;
    const int lab = labels[row];

    const fvec4* __restrict__ xr = (const fvec4*)(x + (size_t)row * FEAT_DIM);
    const fvec4* __restrict__ cr = (const fvec4*)(centers + (size_t)lab * FEAT_DIM);

    // Stage ALL loads first: 8 x-float4 (nontemporal: zero reuse) + 8 c-float4
    // (cached: ~11x reuse across rows). 16 outstanding 16B loads per lane.
    fvec4 xv[8], cv[8];
#pragma unroll
    for (int k = 0; k < 8; ++k)
        xv[k] = __builtin_nontemporal_load(xr + lane + k * 64);
#pragma unroll
    for (int k = 0; k < 8; ++k)
        cv[k] = cr[lane + k * 64];

    float acc = 0.0f;
#pragma unroll
    for (int k = 0; k < 8; ++k) {
        const fvec4 d = xv[k] - cv[k];
        acc += d.x * d.x + d.y * d.y + d.z * d.z + d.w * d.w;
    }

    // wave(64) shuffle reduction
#pragma unroll
    for (int off = 32; off > 0; off >>= 1)
        acc += __shfl_down(acc, off, 64);

    __shared__ float ws[4];
    if (lane == 0)
        ws[wave] = fminf(fmaxf(acc, 1e-12f), 1e12f);  // clamp is per-row
    __syncthreads();

    if (t == 0)
        partial[blockIdx.x] = ws[0] + ws[1] + ws[2] + ws[3];
}

__global__ __launch_bounds__(256) void center_loss_reduce(
        const float* __restrict__ partial,
        float* __restrict__ out) {
    const int t = threadIdx.x;
    float s = 0.0f;
#pragma unroll
    for (int i = 0; i < NB / 256; ++i)
        s += partial[t + i * 256];

#pragma unroll
    for (int off = 32; off > 0; off >>= 1)
        s += __shfl_down(s, off, 64);

    __shared__ float ws[4];
    if ((t & 63) == 0) ws[t >> 6] = s;
    __syncthreads();

    if (t == 0) {
        // masked-out zeros -> clamp to 1e-12: B*(C-1)*1e-12 total, /B -> 7.5e-10
        out[0] = (ws[0] + ws[1] + ws[2] + ws[3]) * (1.0f / BATCH) + 7.5e-10f;
    }
}

extern "C" void kernel_launch(void* const* d_in, const int* in_sizes, int n_in,
                              void* d_out, int out_size, void* d_ws, size_t ws_size,
                              hipStream_t stream) {
    const float* x = (const float*)d_in[0];
    const int* labels = (const int*)d_in[1];
    const float* centers = (const float*)d_in[2];
    float* out = (float*)d_out;
    float* partial = (float*)d_ws;   // NB floats = 8 KB scratch

    center_loss_main<<<NB, 256, 0, stream>>>(x, labels, centers, partial);
    center_loss_reduce<<<1, 256, 0, stream>>>(partial, out);
}